// Round 4
// baseline (438.499 us; speedup 1.0000x reference)
//
#include <hip/hip_runtime.h>

#define NA 50000
#define NT 25000
#define EAA 800000
#define EAT 400000
#define ETA 400000
#define NSEG 125000          // NA + NA + NT rows: [aa | ta | at]
#define TOTAL_E 1600000

// ---- workspace layout (4-byte element offsets) ----
#define O_DEGC    0          // int[125008]: concat degrees  aa-dst[NA] | ta-dst[NA] | at-dst[NT]
#define O_ATSRC   125008     // int[50000]: at-relation src out-degree (over NA)
#define O_TASRC   175008     // int[25000]: ta-relation src out-degree (over NT)
#define O_ZEND    200032     // memset 0 .. here
#define O_RO      200032     // int[125008]: CSR row offsets (global into edge buffer)
#define O_CUR     325040     // int[125000]: fill cursors
#define O_BSUM    450040     // int[512]: scan block sums
#define O_CAA     450552     // float[50000]: rsqrt(indeg_aa+1)
#define O_CTAD    500552     // float[50000]: ta dst coef (over NA)
#define O_CATD    550552     // float[25000]: at dst coef (over NT)
#define O_CATS    575552     // float[50000]: at src coef (over NA)
#define O_CTAS    625552     // float[25000]: ta src coef (over NT)
#define O_U       650552     // float[512]: U_aa[128] | U_ta[128] | U_at[128] | v[4]
#define O_P       651064     // float[100000]: p' = (h_a @ U_aa) * c_aa
#define O_Q       751064     // float[100000]: q' = (h_a @ U_at) * c_ats
#define O_R       851064     // float[50000]:  r' = (h_t @ U_ta) * c_tas
#define O_CSR     901064     // ushort[1600000]: src index only (2B entries)
// total 901064*4 + 3.2MB = 6.8 MB

// ---------- fused degree counting over all 3 relations ----------
__global__ void deg_all_kernel(const int* __restrict__ dst_aa,
                               const int* __restrict__ src_ta, const int* __restrict__ dst_ta,
                               const int* __restrict__ src_at, const int* __restrict__ dst_at,
                               int* __restrict__ wi) {
    int t = blockIdx.x * blockDim.x + threadIdx.x;
    if (t < EAA) {
        atomicAdd(&wi[O_DEGC + dst_aa[t]], 1);
    } else if (t < EAA + ETA) {
        int u = t - EAA;
        atomicAdd(&wi[O_DEGC + NA + dst_ta[u]], 1);
        atomicAdd(&wi[O_TASRC + src_ta[u]], 1);
    } else if (t < TOTAL_E) {
        int u = t - EAA - ETA;
        atomicAdd(&wi[O_DEGC + 2 * NA + dst_at[u]], 1);
        atomicAdd(&wi[O_ATSRC + src_at[u]], 1);
    }
}

// ---------- degrees -> normalization coefficients ----------
__global__ void coef_kernel(const int* __restrict__ wi, float* __restrict__ wf) {
    int t = blockIdx.x * blockDim.x + threadIdx.x;
    if (t < 50000) {
        wf[O_CAA + t] = rsqrtf((float)wi[O_DEGC + t] + 1.0f);
    } else if (t < 100000) {
        int i = t - 50000; int d = wi[O_DEGC + NA + i];
        wf[O_CTAD + i] = d > 0 ? rsqrtf((float)d) : 0.0f;
    } else if (t < 125000) {
        int i = t - 100000; int d = wi[O_DEGC + 2 * NA + i];
        wf[O_CATD + i] = d > 0 ? rsqrtf((float)d) : 0.0f;
    } else if (t < 175000) {
        int i = t - 125000; int d = wi[O_ATSRC + i];
        wf[O_CATS + i] = d > 0 ? rsqrtf((float)d) : 0.0f;
    } else if (t < 200000) {
        int i = t - 175000; int d = wi[O_TASRC + i];
        wf[O_CTAS + i] = d > 0 ? rsqrtf((float)d) : 0.0f;
    }
}

// ---------- 3-kernel exclusive scan over degc[125000] ----------
__global__ void scan1_kernel(const int* __restrict__ degc, int* __restrict__ bsum) {
    __shared__ int s[256];
    int tid = threadIdx.x;
    int g = blockIdx.x * 256 + tid;
    s[tid] = (g < NSEG) ? degc[g] : 0;
    __syncthreads();
    for (int off = 128; off; off >>= 1) {
        if (tid < off) s[tid] += s[tid + off];
        __syncthreads();
    }
    if (tid == 0) bsum[blockIdx.x] = s[0];
}

__global__ void scan2_kernel(int* __restrict__ bsum, int nb) {
    __shared__ int s[512];
    int t = threadIdx.x;
    int v = (t < nb) ? bsum[t] : 0;
    s[t] = v;
    __syncthreads();
    for (int off = 1; off < 512; off <<= 1) {
        int x = (t >= off) ? s[t - off] : 0;
        __syncthreads();
        s[t] += x;
        __syncthreads();
    }
    if (t < nb) bsum[t] = s[t] - v;   // exclusive
}

__global__ void scan3_kernel(const int* __restrict__ degc, const int* __restrict__ bsum,
                             int* __restrict__ ro, int* __restrict__ cur) {
    __shared__ int s[256];
    int tid = threadIdx.x;
    int g = blockIdx.x * 256 + tid;
    int v = (g < NSEG) ? degc[g] : 0;
    s[tid] = v;
    __syncthreads();
    for (int off = 1; off < 256; off <<= 1) {
        int x = (tid >= off) ? s[tid - off] : 0;
        __syncthreads();
        s[tid] += x;
        __syncthreads();
    }
    int excl = s[tid] - v + bsum[blockIdx.x];
    if (g < NSEG) { ro[g] = excl; cur[g] = excl; }
    if (g == 0) ro[NSEG] = TOTAL_E;
}

// ---------- fused CSR fill: pos = cursor[row]++, one 2B src store (nt) ----------
__global__ void fill_all_kernel(const int* __restrict__ src_aa, const int* __restrict__ dst_aa,
                                const int* __restrict__ src_ta, const int* __restrict__ dst_ta,
                                const int* __restrict__ src_at, const int* __restrict__ dst_at,
                                int* __restrict__ cur, unsigned short* __restrict__ csr) {
    int t = blockIdx.x * blockDim.x + threadIdx.x;
    int s, d, base;
    if (t < EAA) {
        s = src_aa[t]; d = dst_aa[t]; base = 0;
    } else if (t < EAA + ETA) {
        int u = t - EAA;
        s = src_ta[u]; d = dst_ta[u]; base = NA;
    } else if (t < TOTAL_E) {
        int u = t - EAA - ETA;
        s = src_at[u]; d = dst_at[u]; base = 2 * NA;
    } else return;
    int pos = atomicAdd(&cur[base + d], 1);
    __builtin_nontemporal_store((unsigned short)s, &csr[pos]);
}

// ---------- fuse conv2 weights with output projection: U_* = W2_* @ Wp_* ----------
__global__ void fuse_kernel(const float* __restrict__ W2_aa, const float* __restrict__ W2_ta,
                            const float* __restrict__ W2_at, const float* __restrict__ b2_aa,
                            const float* __restrict__ b2_ta, const float* __restrict__ b2_at,
                            const float* __restrict__ Wp_a, const float* __restrict__ bp_a,
                            const float* __restrict__ Wp_t, const float* __restrict__ bp_t,
                            float* __restrict__ U) {
    int t = threadIdx.x;  // 512-thread single block
    if (t < 128) {
        int k = t >> 1, j = t & 1;
        float a = 0.f;
        for (int f = 0; f < 64; ++f) a = fmaf(W2_aa[k * 64 + f], Wp_a[f * 2 + j], a);
        U[t] = a;
    } else if (t < 256) {
        int u = t - 128; int k = u >> 1, j = u & 1;
        float a = 0.f;
        for (int f = 0; f < 64; ++f) a = fmaf(W2_ta[k * 64 + f], Wp_a[f * 2 + j], a);
        U[128 + u] = a;
    } else if (t < 384) {
        int u = t - 256; int k = u >> 1, j = u & 1;
        float a = 0.f;
        for (int f = 0; f < 64; ++f) a = fmaf(W2_at[k * 64 + f], Wp_t[f * 2 + j], a);
        U[256 + u] = a;
    } else if (t < 386) {
        int j = t - 384;
        float a = bp_a[j];
        for (int f = 0; f < 64; ++f) a = fmaf(b2_aa[f] + b2_ta[f], Wp_a[f * 2 + j], a);
        U[384 + j] = a;
    } else if (t < 388) {
        int j = t - 386;
        float a = bp_t[j];
        for (int f = 0; f < 64; ++f) a = fmaf(b2_at[f], Wp_t[f * 2 + j], a);
        U[386 + j] = a;
    }
}

// ---------- conv1 agents: float4 gather (8 edges/wave-iter) -> @W1 -> relu -> U-reduce -> p',q' ----------
// one wave per node; 4 nodes per 256-thread block; NA = 12500 * 4 exactly.
__global__ void __launch_bounds__(256)
conv1_agents_kernel(const float* __restrict__ x_a, const float* __restrict__ x_t,
                    const int* __restrict__ ro, const unsigned short* __restrict__ csr,
                    const float* __restrict__ c_aa, const float* __restrict__ c_ta_d,
                    const float* __restrict__ c_ta_s, const float* __restrict__ c_at_s,
                    const float* __restrict__ W_aa, const float* __restrict__ b_aa,
                    const float* __restrict__ W_ta, const float* __restrict__ b_ta,
                    const float* __restrict__ U,
                    float* __restrict__ p, float* __restrict__ q) {
    __shared__ float sWa[32 * 64];
    __shared__ float sWt[32 * 64];
    __shared__ float sAgg[4][2][32];
    for (int i = threadIdx.x; i < 2048; i += 256) {
        sWa[i] = W_aa[i];
        sWt[i] = W_ta[i];
    }
    int lane = threadIdx.x & 63;
    int wave = threadIdx.x >> 6;
    int e8 = lane >> 3, k4 = lane & 7;   // edge slot / float4 slice
    int i = blockIdx.x * 4 + wave;
    float ci = c_aa[i];

    // aa gather: 8 edges in parallel, each covered by 8 lanes x float4
    float4 accA = make_float4(0.f, 0.f, 0.f, 0.f);
    int e0 = ro[i + 1];
    for (int j = ro[i] + e8; j < e0; j += 8) {
        int s = csr[j];
        float w = c_aa[s];
        float4 xv = *(const float4*)(x_a + (size_t)s * 32 + k4 * 4);
        accA.x = fmaf(xv.x, w, accA.x);
        accA.y = fmaf(xv.y, w, accA.y);
        accA.z = fmaf(xv.z, w, accA.z);
        accA.w = fmaf(xv.w, w, accA.w);
    }
    if (e8 == 0) {  // self-loop term
        float4 xv = *(const float4*)(x_a + (size_t)i * 32 + k4 * 4);
        accA.x = fmaf(xv.x, ci, accA.x);
        accA.y = fmaf(xv.y, ci, accA.y);
        accA.z = fmaf(xv.z, ci, accA.z);
        accA.w = fmaf(xv.w, ci, accA.w);
    }
    // ta gather
    float4 accT = make_float4(0.f, 0.f, 0.f, 0.f);
    int e1 = ro[NA + i + 1];
    for (int j = ro[NA + i] + e8; j < e1; j += 8) {
        int s = csr[j];
        float w = c_ta_s[s];
        float4 xv = *(const float4*)(x_t + (size_t)s * 32 + k4 * 4);
        accT.x = fmaf(xv.x, w, accT.x);
        accT.y = fmaf(xv.y, w, accT.y);
        accT.z = fmaf(xv.z, w, accT.z);
        accT.w = fmaf(xv.w, w, accT.w);
    }
    // reduce over the 8 edge slots
#pragma unroll
    for (int m = 8; m <= 32; m <<= 1) {
        accA.x += __shfl_xor(accA.x, m, 64);
        accA.y += __shfl_xor(accA.y, m, 64);
        accA.z += __shfl_xor(accA.z, m, 64);
        accA.w += __shfl_xor(accA.w, m, 64);
        accT.x += __shfl_xor(accT.x, m, 64);
        accT.y += __shfl_xor(accT.y, m, 64);
        accT.z += __shfl_xor(accT.z, m, 64);
        accT.w += __shfl_xor(accT.w, m, 64);
    }
    if (lane < 8) {
        float cta = c_ta_d[i];
        *(float4*)&sAgg[wave][0][k4 * 4] =
            make_float4(accA.x * ci, accA.y * ci, accA.z * ci, accA.w * ci);
        *(float4*)&sAgg[wave][1][k4 * 4] =
            make_float4(accT.x * cta, accT.y * cta, accT.z * cta, accT.w * cta);
    }
    __syncthreads();
    // matvec: h[lane] = relu(bias + agg_aa @ W_aa[:,lane] + agg_ta @ W_ta[:,lane])
    float h = b_aa[lane] + b_ta[lane];
#pragma unroll
    for (int kk = 0; kk < 32; ++kk) {
        h = fmaf(sAgg[wave][0][kk], sWa[kk * 64 + lane], h);
        h = fmaf(sAgg[wave][1][kk], sWt[kk * 64 + lane], h);
    }
    h = fmaxf(h, 0.f);
    // reduce h against U_aa (->p) and U_at (->q)
    float p0 = h * U[lane * 2], p1 = h * U[lane * 2 + 1];
    float q0 = h * U[256 + lane * 2], q1 = h * U[256 + lane * 2 + 1];
#pragma unroll
    for (int m = 32; m; m >>= 1) {
        p0 += __shfl_xor(p0, m, 64);
        p1 += __shfl_xor(p1, m, 64);
        q0 += __shfl_xor(q0, m, 64);
        q1 += __shfl_xor(q1, m, 64);
    }
    if (lane == 0) {
        float cq = c_at_s[i];
        *(float2*)&p[i * 2] = make_float2(p0 * ci, p1 * ci);   // p' = p * c_aa
        *(float2*)&q[i * 2] = make_float2(q0 * cq, q1 * cq);   // q' = q * c_at_src
    }
}

// ---------- conv1 targets: float4 gather(at) -> @W1_at -> relu -> U_ta-reduce -> r' ----------
__global__ void __launch_bounds__(256)
conv1_targets_kernel(const float* __restrict__ x_a, const int* __restrict__ ro,
                     const unsigned short* __restrict__ csr, const float* __restrict__ c_at_d,
                     const float* __restrict__ c_at_s, const float* __restrict__ c_ta_s,
                     const float* __restrict__ W_at, const float* __restrict__ b_at,
                     const float* __restrict__ U, float* __restrict__ r) {
    __shared__ float sW[32 * 64];
    __shared__ float sAgg[4][32];
    for (int i = threadIdx.x; i < 2048; i += 256) sW[i] = W_at[i];
    int lane = threadIdx.x & 63;
    int wave = threadIdx.x >> 6;
    int e8 = lane >> 3, k4 = lane & 7;
    int i = blockIdx.x * 4 + wave;

    float4 acc = make_float4(0.f, 0.f, 0.f, 0.f);
    int e0 = ro[2 * NA + i + 1];
    for (int j = ro[2 * NA + i] + e8; j < e0; j += 8) {
        int s = csr[j];
        float w = c_at_s[s];
        float4 xv = *(const float4*)(x_a + (size_t)s * 32 + k4 * 4);
        acc.x = fmaf(xv.x, w, acc.x);
        acc.y = fmaf(xv.y, w, acc.y);
        acc.z = fmaf(xv.z, w, acc.z);
        acc.w = fmaf(xv.w, w, acc.w);
    }
#pragma unroll
    for (int m = 8; m <= 32; m <<= 1) {
        acc.x += __shfl_xor(acc.x, m, 64);
        acc.y += __shfl_xor(acc.y, m, 64);
        acc.z += __shfl_xor(acc.z, m, 64);
        acc.w += __shfl_xor(acc.w, m, 64);
    }
    if (lane < 8) {
        float cd = c_at_d[i];
        *(float4*)&sAgg[wave][k4 * 4] =
            make_float4(acc.x * cd, acc.y * cd, acc.z * cd, acc.w * cd);
    }
    __syncthreads();
    float h = b_at[lane];
#pragma unroll
    for (int kk = 0; kk < 32; ++kk) h = fmaf(sAgg[wave][kk], sW[kk * 64 + lane], h);
    h = fmaxf(h, 0.f);
    float r0 = h * U[128 + lane * 2], r1 = h * U[128 + lane * 2 + 1];
#pragma unroll
    for (int m = 32; m; m >>= 1) {
        r0 += __shfl_xor(r0, m, 64);
        r1 += __shfl_xor(r1, m, 64);
    }
    if (lane == 0) {
        float cr = c_ta_s[i];
        *(float2*)&r[i * 2] = make_float2(r0 * cr, r1 * cr);   // r' = r * c_ta_src
    }
}

// ---------- conv2+proj combined: 8 threads/node (4 edge slots x 2 comps) ----------
__global__ void __launch_bounds__(256)
out_all_kernel(const float* __restrict__ p, const float* __restrict__ q,
               const float* __restrict__ r, const int* __restrict__ ro,
               const unsigned short* __restrict__ csr,
               const float* __restrict__ c_aa, const float* __restrict__ c_ta_d,
               const float* __restrict__ c_at_d, const float* __restrict__ U,
               float* __restrict__ out) {
    int t = blockIdx.x * blockDim.x + threadIdx.x;
    if (t < NA * 8) {
        int i = t >> 3, sub = t & 7, slot = sub >> 1, j = sub & 1;
        float ci = c_aa[i];
        float accA = (slot == 0) ? p[i * 2 + j] : 0.f;   // self-loop (p already * c_aa)
        int e0 = ro[i + 1];
        for (int jj = ro[i] + slot; jj < e0; jj += 4)
            accA += p[csr[jj] * 2 + j];
        float accT = 0.f;
        int e1 = ro[NA + i + 1];
        for (int jj = ro[NA + i] + slot; jj < e1; jj += 4)
            accT += r[csr[jj] * 2 + j];
        accA += __shfl_xor(accA, 2, 64);
        accA += __shfl_xor(accA, 4, 64);
        accT += __shfl_xor(accT, 2, 64);
        accT += __shfl_xor(accT, 4, 64);
        if (slot == 0)
            out[i * 2 + j] = U[384 + j] + accA * ci + accT * c_ta_d[i];
    } else if (t < (NA + NT) * 8) {
        int u = t - NA * 8;
        int i = u >> 3, sub = u & 7, slot = sub >> 1, j = sub & 1;
        float acc = 0.f;
        int e0 = ro[2 * NA + i + 1];
        for (int jj = ro[2 * NA + i] + slot; jj < e0; jj += 4)
            acc += q[csr[jj] * 2 + j];
        acc += __shfl_xor(acc, 2, 64);
        acc += __shfl_xor(acc, 4, 64);
        if (slot == 0)
            out[NA * 2 + i * 2 + j] = U[386 + j] + acc * c_at_d[i];
    }
}

extern "C" void kernel_launch(void* const* d_in, const int* in_sizes, int n_in,
                              void* d_out, int out_size, void* d_ws, size_t ws_size,
                              hipStream_t stream) {
    const float* x_a   = (const float*)d_in[1];
    const float* x_t   = (const float*)d_in[2];
    const int* src_aa  = (const int*)d_in[3];
    const int* dst_aa  = (const int*)d_in[4];
    const int* src_at  = (const int*)d_in[5];
    const int* dst_at  = (const int*)d_in[6];
    const int* src_ta  = (const int*)d_in[7];
    const int* dst_ta  = (const int*)d_in[8];
    const float* W1_aa = (const float*)d_in[9];
    const float* b1_aa = (const float*)d_in[10];
    const float* W1_at = (const float*)d_in[11];
    const float* b1_at = (const float*)d_in[12];
    const float* W1_ta = (const float*)d_in[13];
    const float* b1_ta = (const float*)d_in[14];
    const float* W2_aa = (const float*)d_in[15];
    const float* b2_aa = (const float*)d_in[16];
    const float* W2_at = (const float*)d_in[17];
    const float* b2_at = (const float*)d_in[18];
    const float* W2_ta = (const float*)d_in[19];
    const float* b2_ta = (const float*)d_in[20];
    const float* Wp_a  = (const float*)d_in[21];
    const float* bp_a  = (const float*)d_in[22];
    const float* Wp_t  = (const float*)d_in[23];
    const float* bp_t  = (const float*)d_in[24];

    int*   wi  = (int*)d_ws;
    float* wf  = (float*)d_ws;
    unsigned short* csr = (unsigned short*)((int*)d_ws + O_CSR);
    float* out = (float*)d_out;

    const int B = 256;
    auto blk = [](int n) { return (n + 255) / 256; };
    const int NB_SCAN = (NSEG + 255) / 256;   // 489

    // zero the degree histograms
    hipMemsetAsync(wi, 0, (size_t)O_ZEND * 4, stream);

    // degrees (fused, int histograms)
    deg_all_kernel<<<blk(TOTAL_E), B, 0, stream>>>(dst_aa, src_ta, dst_ta, src_at, dst_at, wi);

    // coefficients
    coef_kernel<<<blk(200000), B, 0, stream>>>(wi, wf);

    // CSR row offsets (exclusive scan over concatenated degrees)
    scan1_kernel<<<NB_SCAN, 256, 0, stream>>>(wi + O_DEGC, wi + O_BSUM);
    scan2_kernel<<<1, 512, 0, stream>>>(wi + O_BSUM, NB_SCAN);
    scan3_kernel<<<NB_SCAN, 256, 0, stream>>>(wi + O_DEGC, wi + O_BSUM, wi + O_RO, wi + O_CUR);

    // fused CSR fill (2B src-only entries, nt stores)
    fill_all_kernel<<<blk(TOTAL_E), B, 0, stream>>>(src_aa, dst_aa, src_ta, dst_ta,
                                                    src_at, dst_at, wi + O_CUR, csr);

    // fuse conv2 weights with output projection
    fuse_kernel<<<1, 512, 0, stream>>>(W2_aa, W2_ta, W2_at, b2_aa, b2_ta, b2_at,
                                       Wp_a, bp_a, Wp_t, bp_t, wf + O_U);

    // conv1 (float4 gather + transform + relu + U-reduction), writes p',q',r'
    conv1_agents_kernel<<<NA / 4, 256, 0, stream>>>(
        x_a, x_t, wi + O_RO, csr, wf + O_CAA, wf + O_CTAD, wf + O_CTAS, wf + O_CATS,
        W1_aa, b1_aa, W1_ta, b1_ta, wf + O_U, wf + O_P, wf + O_Q);
    conv1_targets_kernel<<<NT / 4, 256, 0, stream>>>(
        x_a, wi + O_RO, csr, wf + O_CATD, wf + O_CATS, wf + O_CTAS,
        W1_at, b1_at, wf + O_U, wf + O_R);

    // conv2 + projection via gather, direct to output (fused agents+targets)
    out_all_kernel<<<blk((NA + NT) * 8), B, 0, stream>>>(
        wf + O_P, wf + O_Q, wf + O_R, wi + O_RO, csr,
        wf + O_CAA, wf + O_CTAD, wf + O_CATD, wf + O_U, out);
}

// Round 5
// 354.770 us; speedup vs baseline: 1.2360x; 1.2360x over previous
//
#include <hip/hip_runtime.h>

#define NA 50000
#define NT 25000
#define EAA 800000
#define EAT 400000
#define ETA 400000
#define NSEG 125000          // NA + NA + NT rows: [aa | ta | at]
#define TOTAL_E 1600000
#define NB 245               // coarse buckets of 512 rows
#define NBLK1 196            // pass-1 blocks
#define CHUNK 8192           // edges per pass-1 block

// ---- workspace layout (4-byte element offsets) ----
#define O_HIST    0          // int[48020]: hist[bucket][block] -> scanned bases
#define O_ATSRC   48064      // int[50000]: at-relation src out-degree (over NA)
#define O_TASRC   98064      // int[25000]: ta-relation src out-degree (over NT)
#define O_RO      123072     // int[125001]: CSR row offsets
#define O_CAA     248128     // float[50000]: rsqrt(indeg_aa+1)
#define O_CTAD    298128     // float[50000]: ta dst coef (over NA)
#define O_CATD    348128     // float[25000]: at dst coef (over NT)
#define O_CATS    373128     // float[50000]: at src coef (over NA)
#define O_CTAS    423128     // float[25000]: ta src coef (over NT)
#define O_U       448128     // float[512]: U_aa[128] | U_ta[128] | U_at[128] | v[4]
#define O_P       448640     // float[100000]: p' = (h_a @ U_aa) * c_aa
#define O_Q       548640     // float[100000]: q' = (h_a @ U_at) * c_ats
#define O_R       648640     // float[50000]:  r' = (h_t @ U_ta) * c_tas
#define O_REC     698640     // int[1600000]: packed records (row_local<<16)|src
#define O_CSR     2298640    // ushort[1600000]: final CSR src indices
// total ~3.1M ints = 12.4 MB

// ---------- pass 1a: per-block coarse histogram (LDS only, no global atomics) ----------
__global__ void __launch_bounds__(256)
p1_hist_kernel(const int* __restrict__ dst_aa, const int* __restrict__ dst_ta,
               const int* __restrict__ dst_at, int* __restrict__ hist_g) {
    __shared__ int h[NB];
    for (int i = threadIdx.x; i < NB; i += 256) h[i] = 0;
    __syncthreads();
    int b = blockIdx.x;
    int t0 = b * CHUNK, t1 = min(t0 + CHUNK, TOTAL_E);
    for (int t = t0 + threadIdx.x; t < t1; t += 256) {
        int row;
        if (t < EAA) row = dst_aa[t];
        else if (t < EAA + ETA) row = NA + dst_ta[t - EAA];
        else row = 2 * NA + dst_at[t - EAA - ETA];
        atomicAdd(&h[row >> 9], 1);
    }
    __syncthreads();
    for (int i = threadIdx.x; i < NB; i += 256) hist_g[i * NBLK1 + b] = h[i];
}

// ---------- pass 1b: single-block exclusive scan of hist[NB*NBLK1] (wave shfl scan) ----------
__global__ void __launch_bounds__(1024)
p1_scan_kernel(int* __restrict__ h) {
    __shared__ int wsum[16];
    __shared__ int sCarry;
    int tid = threadIdx.x, lane = tid & 63, wid = tid >> 6;
    if (tid == 0) sCarry = 0;
    __syncthreads();
    const int N2 = NB * NBLK1;
    for (int base = 0; base < N2; base += 1024) {
        int idx = base + tid;
        int v = (idx < N2) ? h[idx] : 0;
        int x = v;
#pragma unroll
        for (int off = 1; off < 64; off <<= 1) {
            int y = __shfl_up(x, off, 64);
            if (lane >= off) x += y;
        }
        if (lane == 63) wsum[wid] = x;
        __syncthreads();
        int wpre = 0, tot = 0;
        for (int w = 0; w < 16; ++w) {
            int s = wsum[w];
            if (w < wid) wpre += s;
            tot += s;
        }
        int excl = x - v + wpre + sCarry;
        if (idx < N2) h[idx] = excl;
        __syncthreads();
        if (tid == 0) sCarry += tot;
        __syncthreads();
    }
}

// ---------- pass 1c: scatter packed records via LDS cursors (block-exclusive runs) ----------
__global__ void __launch_bounds__(256)
p1_scatter_kernel(const int* __restrict__ src_aa, const int* __restrict__ dst_aa,
                  const int* __restrict__ src_ta, const int* __restrict__ dst_ta,
                  const int* __restrict__ src_at, const int* __restrict__ dst_at,
                  const int* __restrict__ hist_g, int* __restrict__ rec) {
    __shared__ int cur[NB];
    int b = blockIdx.x;
    for (int i = threadIdx.x; i < NB; i += 256) cur[i] = hist_g[i * NBLK1 + b];
    __syncthreads();
    int t0 = b * CHUNK, t1 = min(t0 + CHUNK, TOTAL_E);
    for (int t = t0 + threadIdx.x; t < t1; t += 256) {
        int row, s;
        if (t < EAA) { row = dst_aa[t]; s = src_aa[t]; }
        else if (t < EAA + ETA) { int u = t - EAA; row = NA + dst_ta[u]; s = src_ta[u]; }
        else { int u = t - EAA - ETA; row = 2 * NA + dst_at[u]; s = src_at[u]; }
        int pos = atomicAdd(&cur[row >> 9], 1);
        rec[pos] = ((row & 511) << 16) | s;
    }
}

// ---------- src-side degree counting (only remaining global atomics: 800K) ----------
__global__ void srcdeg_kernel(const int* __restrict__ src_at, const int* __restrict__ src_ta,
                              int* __restrict__ wi) {
    int t = blockIdx.x * blockDim.x + threadIdx.x;
    if (t < EAT) atomicAdd(&wi[O_ATSRC + src_at[t]], 1);
    else if (t < EAT + ETA) atomicAdd(&wi[O_TASRC + src_ta[t - EAT]], 1);
}

__global__ void coef2_kernel(const int* __restrict__ wi, float* __restrict__ wf) {
    int t = blockIdx.x * blockDim.x + threadIdx.x;
    if (t < 50000) {
        int d = wi[O_ATSRC + t];
        wf[O_CATS + t] = d > 0 ? rsqrtf((float)d) : 0.0f;
    } else if (t < 75000) {
        int i = t - 50000; int d = wi[O_TASRC + i];
        wf[O_CTAS + i] = d > 0 ? rsqrtf((float)d) : 0.0f;
    }
}

// ---------- pass 2: per-bucket degree count + LDS scan -> ro + dst coefs + CSR scatter ----------
__global__ void __launch_bounds__(256)
p2_kernel(const int* __restrict__ hist_g, const int* __restrict__ rec,
          int* __restrict__ ro, float* __restrict__ caa, float* __restrict__ ctad,
          float* __restrict__ catd, unsigned short* __restrict__ csr) {
    __shared__ int deg[512];
    __shared__ int rb[512];
    __shared__ int wsum[4];
    int k = blockIdx.x, tid = threadIdx.x, lane = tid & 63, wid = tid >> 6;
    int e0 = hist_g[k * NBLK1];
    int e1 = (k + 1 < NB) ? hist_g[(k + 1) * NBLK1] : TOTAL_E;
    deg[tid] = 0; deg[tid + 256] = 0;
    __syncthreads();
    for (int j = e0 + tid; j < e1; j += 256) atomicAdd(&deg[rec[j] >> 16], 1);
    __syncthreads();
    // exclusive scan of deg[512]: pair-sum then 256-scan then expand
    int d0 = deg[2 * tid], d1 = deg[2 * tid + 1];
    int v = d0 + d1;
    int x = v;
#pragma unroll
    for (int off = 1; off < 64; off <<= 1) {
        int y = __shfl_up(x, off, 64);
        if (lane >= off) x += y;
    }
    if (lane == 63) wsum[wid] = x;
    __syncthreads();
    int wpre = 0;
    for (int w = 0; w < wid; ++w) wpre += wsum[w];
    int pexcl = x - v + wpre;
    rb[2 * tid] = e0 + pexcl;
    rb[2 * tid + 1] = e0 + pexcl + d0;
    __syncthreads();
    // write ro + dst-side coefficients (coalesced, no atomics)
    for (int i = tid; i < 512; i += 256) {
        int g = k * 512 + i;
        if (g < NSEG) {
            ro[g] = rb[i];
            int d = deg[i];
            if (g < NA) caa[g] = rsqrtf((float)d + 1.0f);
            else if (g < 2 * NA) ctad[g - NA] = d > 0 ? rsqrtf((float)d) : 0.0f;
            else catd[g - 2 * NA] = d > 0 ? rsqrtf((float)d) : 0.0f;
        }
    }
    if (k == NB - 1 && tid == 0) ro[NSEG] = TOTAL_E;
    __syncthreads();
    // scatter CSR entries via LDS cursors into this block's exclusive window
    for (int j = e0 + tid; j < e1; j += 256) {
        int rc = rec[j];
        int pos = atomicAdd(&rb[rc >> 16], 1);
        csr[pos] = (unsigned short)(rc & 0xFFFF);
    }
}

// ---------- fuse conv2 weights with output projection: U_* = W2_* @ Wp_* ----------
__global__ void fuse_kernel(const float* __restrict__ W2_aa, const float* __restrict__ W2_ta,
                            const float* __restrict__ W2_at, const float* __restrict__ b2_aa,
                            const float* __restrict__ b2_ta, const float* __restrict__ b2_at,
                            const float* __restrict__ Wp_a, const float* __restrict__ bp_a,
                            const float* __restrict__ Wp_t, const float* __restrict__ bp_t,
                            float* __restrict__ U) {
    int t = threadIdx.x;  // 512-thread single block
    if (t < 128) {
        int k = t >> 1, j = t & 1;
        float a = 0.f;
        for (int f = 0; f < 64; ++f) a = fmaf(W2_aa[k * 64 + f], Wp_a[f * 2 + j], a);
        U[t] = a;
    } else if (t < 256) {
        int u = t - 128; int k = u >> 1, j = u & 1;
        float a = 0.f;
        for (int f = 0; f < 64; ++f) a = fmaf(W2_ta[k * 64 + f], Wp_a[f * 2 + j], a);
        U[128 + u] = a;
    } else if (t < 384) {
        int u = t - 256; int k = u >> 1, j = u & 1;
        float a = 0.f;
        for (int f = 0; f < 64; ++f) a = fmaf(W2_at[k * 64 + f], Wp_t[f * 2 + j], a);
        U[256 + u] = a;
    } else if (t < 386) {
        int j = t - 384;
        float a = bp_a[j];
        for (int f = 0; f < 64; ++f) a = fmaf(b2_aa[f] + b2_ta[f], Wp_a[f * 2 + j], a);
        U[384 + j] = a;
    } else if (t < 388) {
        int j = t - 386;
        float a = bp_t[j];
        for (int f = 0; f < 64; ++f) a = fmaf(b2_at[f], Wp_t[f * 2 + j], a);
        U[386 + j] = a;
    }
}

// ---------- conv1 agents: float4 gather (8 edges/wave-iter) -> @W1 -> relu -> U-reduce -> p',q' ----------
__global__ void __launch_bounds__(256)
conv1_agents_kernel(const float* __restrict__ x_a, const float* __restrict__ x_t,
                    const int* __restrict__ ro, const unsigned short* __restrict__ csr,
                    const float* __restrict__ c_aa, const float* __restrict__ c_ta_d,
                    const float* __restrict__ c_ta_s, const float* __restrict__ c_at_s,
                    const float* __restrict__ W_aa, const float* __restrict__ b_aa,
                    const float* __restrict__ W_ta, const float* __restrict__ b_ta,
                    const float* __restrict__ U,
                    float* __restrict__ p, float* __restrict__ q) {
    __shared__ float sWa[32 * 64];
    __shared__ float sWt[32 * 64];
    __shared__ float sAgg[4][2][32];
    for (int i = threadIdx.x; i < 2048; i += 256) {
        sWa[i] = W_aa[i];
        sWt[i] = W_ta[i];
    }
    int lane = threadIdx.x & 63;
    int wave = threadIdx.x >> 6;
    int e8 = lane >> 3, k4 = lane & 7;   // edge slot / float4 slice
    int i = blockIdx.x * 4 + wave;
    float ci = c_aa[i];

    float4 accA = make_float4(0.f, 0.f, 0.f, 0.f);
    int e0 = ro[i + 1];
    for (int j = ro[i] + e8; j < e0; j += 8) {
        int s = csr[j];
        float w = c_aa[s];
        float4 xv = *(const float4*)(x_a + (size_t)s * 32 + k4 * 4);
        accA.x = fmaf(xv.x, w, accA.x);
        accA.y = fmaf(xv.y, w, accA.y);
        accA.z = fmaf(xv.z, w, accA.z);
        accA.w = fmaf(xv.w, w, accA.w);
    }
    if (e8 == 0) {  // self-loop term
        float4 xv = *(const float4*)(x_a + (size_t)i * 32 + k4 * 4);
        accA.x = fmaf(xv.x, ci, accA.x);
        accA.y = fmaf(xv.y, ci, accA.y);
        accA.z = fmaf(xv.z, ci, accA.z);
        accA.w = fmaf(xv.w, ci, accA.w);
    }
    float4 accT = make_float4(0.f, 0.f, 0.f, 0.f);
    int e1 = ro[NA + i + 1];
    for (int j = ro[NA + i] + e8; j < e1; j += 8) {
        int s = csr[j];
        float w = c_ta_s[s];
        float4 xv = *(const float4*)(x_t + (size_t)s * 32 + k4 * 4);
        accT.x = fmaf(xv.x, w, accT.x);
        accT.y = fmaf(xv.y, w, accT.y);
        accT.z = fmaf(xv.z, w, accT.z);
        accT.w = fmaf(xv.w, w, accT.w);
    }
#pragma unroll
    for (int m = 8; m <= 32; m <<= 1) {
        accA.x += __shfl_xor(accA.x, m, 64);
        accA.y += __shfl_xor(accA.y, m, 64);
        accA.z += __shfl_xor(accA.z, m, 64);
        accA.w += __shfl_xor(accA.w, m, 64);
        accT.x += __shfl_xor(accT.x, m, 64);
        accT.y += __shfl_xor(accT.y, m, 64);
        accT.z += __shfl_xor(accT.z, m, 64);
        accT.w += __shfl_xor(accT.w, m, 64);
    }
    if (lane < 8) {
        float cta = c_ta_d[i];
        *(float4*)&sAgg[wave][0][k4 * 4] =
            make_float4(accA.x * ci, accA.y * ci, accA.z * ci, accA.w * ci);
        *(float4*)&sAgg[wave][1][k4 * 4] =
            make_float4(accT.x * cta, accT.y * cta, accT.z * cta, accT.w * cta);
    }
    __syncthreads();
    float h = b_aa[lane] + b_ta[lane];
#pragma unroll
    for (int kk = 0; kk < 32; ++kk) {
        h = fmaf(sAgg[wave][0][kk], sWa[kk * 64 + lane], h);
        h = fmaf(sAgg[wave][1][kk], sWt[kk * 64 + lane], h);
    }
    h = fmaxf(h, 0.f);
    float p0 = h * U[lane * 2], p1 = h * U[lane * 2 + 1];
    float q0 = h * U[256 + lane * 2], q1 = h * U[256 + lane * 2 + 1];
#pragma unroll
    for (int m = 32; m; m >>= 1) {
        p0 += __shfl_xor(p0, m, 64);
        p1 += __shfl_xor(p1, m, 64);
        q0 += __shfl_xor(q0, m, 64);
        q1 += __shfl_xor(q1, m, 64);
    }
    if (lane == 0) {
        float cq = c_at_s[i];
        *(float2*)&p[i * 2] = make_float2(p0 * ci, p1 * ci);   // p' = p * c_aa
        *(float2*)&q[i * 2] = make_float2(q0 * cq, q1 * cq);   // q' = q * c_at_src
    }
}

// ---------- conv1 targets ----------
__global__ void __launch_bounds__(256)
conv1_targets_kernel(const float* __restrict__ x_a, const int* __restrict__ ro,
                     const unsigned short* __restrict__ csr, const float* __restrict__ c_at_d,
                     const float* __restrict__ c_at_s, const float* __restrict__ c_ta_s,
                     const float* __restrict__ W_at, const float* __restrict__ b_at,
                     const float* __restrict__ U, float* __restrict__ r) {
    __shared__ float sW[32 * 64];
    __shared__ float sAgg[4][32];
    for (int i = threadIdx.x; i < 2048; i += 256) sW[i] = W_at[i];
    int lane = threadIdx.x & 63;
    int wave = threadIdx.x >> 6;
    int e8 = lane >> 3, k4 = lane & 7;
    int i = blockIdx.x * 4 + wave;

    float4 acc = make_float4(0.f, 0.f, 0.f, 0.f);
    int e0 = ro[2 * NA + i + 1];
    for (int j = ro[2 * NA + i] + e8; j < e0; j += 8) {
        int s = csr[j];
        float w = c_at_s[s];
        float4 xv = *(const float4*)(x_a + (size_t)s * 32 + k4 * 4);
        acc.x = fmaf(xv.x, w, acc.x);
        acc.y = fmaf(xv.y, w, acc.y);
        acc.z = fmaf(xv.z, w, acc.z);
        acc.w = fmaf(xv.w, w, acc.w);
    }
#pragma unroll
    for (int m = 8; m <= 32; m <<= 1) {
        acc.x += __shfl_xor(acc.x, m, 64);
        acc.y += __shfl_xor(acc.y, m, 64);
        acc.z += __shfl_xor(acc.z, m, 64);
        acc.w += __shfl_xor(acc.w, m, 64);
    }
    if (lane < 8) {
        float cd = c_at_d[i];
        *(float4*)&sAgg[wave][k4 * 4] =
            make_float4(acc.x * cd, acc.y * cd, acc.z * cd, acc.w * cd);
    }
    __syncthreads();
    float h = b_at[lane];
#pragma unroll
    for (int kk = 0; kk < 32; ++kk) h = fmaf(sAgg[wave][kk], sW[kk * 64 + lane], h);
    h = fmaxf(h, 0.f);
    float r0 = h * U[128 + lane * 2], r1 = h * U[128 + lane * 2 + 1];
#pragma unroll
    for (int m = 32; m; m >>= 1) {
        r0 += __shfl_xor(r0, m, 64);
        r1 += __shfl_xor(r1, m, 64);
    }
    if (lane == 0) {
        float cr = c_ta_s[i];
        *(float2*)&r[i * 2] = make_float2(r0 * cr, r1 * cr);   // r' = r * c_ta_src
    }
}

// ---------- conv2+proj combined: 8 threads/node (4 edge slots x 2 comps) ----------
__global__ void __launch_bounds__(256)
out_all_kernel(const float* __restrict__ p, const float* __restrict__ q,
               const float* __restrict__ r, const int* __restrict__ ro,
               const unsigned short* __restrict__ csr,
               const float* __restrict__ c_aa, const float* __restrict__ c_ta_d,
               const float* __restrict__ c_at_d, const float* __restrict__ U,
               float* __restrict__ out) {
    int t = blockIdx.x * blockDim.x + threadIdx.x;
    if (t < NA * 8) {
        int i = t >> 3, sub = t & 7, slot = sub >> 1, j = sub & 1;
        float ci = c_aa[i];
        float accA = (slot == 0) ? p[i * 2 + j] : 0.f;   // self-loop (p already * c_aa)
        int e0 = ro[i + 1];
        for (int jj = ro[i] + slot; jj < e0; jj += 4)
            accA += p[csr[jj] * 2 + j];
        float accT = 0.f;
        int e1 = ro[NA + i + 1];
        for (int jj = ro[NA + i] + slot; jj < e1; jj += 4)
            accT += r[csr[jj] * 2 + j];
        accA += __shfl_xor(accA, 2, 64);
        accA += __shfl_xor(accA, 4, 64);
        accT += __shfl_xor(accT, 2, 64);
        accT += __shfl_xor(accT, 4, 64);
        if (slot == 0)
            out[i * 2 + j] = U[384 + j] + accA * ci + accT * c_ta_d[i];
    } else if (t < (NA + NT) * 8) {
        int u = t - NA * 8;
        int i = u >> 3, sub = u & 7, slot = sub >> 1, j = sub & 1;
        float acc = 0.f;
        int e0 = ro[2 * NA + i + 1];
        for (int jj = ro[2 * NA + i] + slot; jj < e0; jj += 4)
            acc += q[csr[jj] * 2 + j];
        acc += __shfl_xor(acc, 2, 64);
        acc += __shfl_xor(acc, 4, 64);
        if (slot == 0)
            out[NA * 2 + i * 2 + j] = U[386 + j] + acc * c_at_d[i];
    }
}

extern "C" void kernel_launch(void* const* d_in, const int* in_sizes, int n_in,
                              void* d_out, int out_size, void* d_ws, size_t ws_size,
                              hipStream_t stream) {
    const float* x_a   = (const float*)d_in[1];
    const float* x_t   = (const float*)d_in[2];
    const int* src_aa  = (const int*)d_in[3];
    const int* dst_aa  = (const int*)d_in[4];
    const int* src_at  = (const int*)d_in[5];
    const int* dst_at  = (const int*)d_in[6];
    const int* src_ta  = (const int*)d_in[7];
    const int* dst_ta  = (const int*)d_in[8];
    const float* W1_aa = (const float*)d_in[9];
    const float* b1_aa = (const float*)d_in[10];
    const float* W1_at = (const float*)d_in[11];
    const float* b1_at = (const float*)d_in[12];
    const float* W1_ta = (const float*)d_in[13];
    const float* b1_ta = (const float*)d_in[14];
    const float* W2_aa = (const float*)d_in[15];
    const float* b2_aa = (const float*)d_in[16];
    const float* W2_at = (const float*)d_in[17];
    const float* b2_at = (const float*)d_in[18];
    const float* W2_ta = (const float*)d_in[19];
    const float* b2_ta = (const float*)d_in[20];
    const float* Wp_a  = (const float*)d_in[21];
    const float* bp_a  = (const float*)d_in[22];
    const float* Wp_t  = (const float*)d_in[23];
    const float* bp_t  = (const float*)d_in[24];

    int*   wi  = (int*)d_ws;
    float* wf  = (float*)d_ws;
    unsigned short* csr = (unsigned short*)(wi + O_CSR);
    float* out = (float*)d_out;

    const int B = 256;
    auto blk = [](int n) { return (n + 255) / 256; };

    // zero only the src-degree histograms (everything else written coalesced)
    hipMemsetAsync(wi + O_ATSRC, 0, 75000 * 4, stream);

    // pass 1: coarse bucket sort of all edges (LDS-privatized, no global atomics)
    p1_hist_kernel<<<NBLK1, 256, 0, stream>>>(dst_aa, dst_ta, dst_at, wi + O_HIST);
    p1_scan_kernel<<<1, 1024, 0, stream>>>(wi + O_HIST);
    p1_scatter_kernel<<<NBLK1, 256, 0, stream>>>(src_aa, dst_aa, src_ta, dst_ta,
                                                 src_at, dst_at, wi + O_HIST, wi + O_REC);

    // src-side degrees (800K global atomics) + coefs
    srcdeg_kernel<<<blk(EAT + ETA), B, 0, stream>>>(src_at, src_ta, wi);
    coef2_kernel<<<blk(75000), B, 0, stream>>>(wi, wf);

    // pass 2: per-bucket -> ro + dst coefs + final CSR (LDS-privatized)
    p2_kernel<<<NB, 256, 0, stream>>>(wi + O_HIST, wi + O_REC, wi + O_RO,
                                      wf + O_CAA, wf + O_CTAD, wf + O_CATD, csr);

    // fuse conv2 weights with output projection
    fuse_kernel<<<1, 512, 0, stream>>>(W2_aa, W2_ta, W2_at, b2_aa, b2_ta, b2_at,
                                       Wp_a, bp_a, Wp_t, bp_t, wf + O_U);

    // conv1 (float4 gather + transform + relu + U-reduction), writes p',q',r'
    conv1_agents_kernel<<<NA / 4, 256, 0, stream>>>(
        x_a, x_t, wi + O_RO, csr, wf + O_CAA, wf + O_CTAD, wf + O_CTAS, wf + O_CATS,
        W1_aa, b1_aa, W1_ta, b1_ta, wf + O_U, wf + O_P, wf + O_Q);
    conv1_targets_kernel<<<NT / 4, 256, 0, stream>>>(
        x_a, wi + O_RO, csr, wf + O_CATD, wf + O_CATS, wf + O_CTAS,
        W1_at, b1_at, wf + O_U, wf + O_R);

    // conv2 + projection via gather, direct to output (fused agents+targets)
    out_all_kernel<<<blk((NA + NT) * 8), B, 0, stream>>>(
        wf + O_P, wf + O_Q, wf + O_R, wi + O_RO, csr,
        wf + O_CAA, wf + O_CTAD, wf + O_CATD, wf + O_U, out);
}

// Round 6
// 332.094 us; speedup vs baseline: 1.3204x; 1.0683x over previous
//
#include <hip/hip_runtime.h>

#define NA 50000
#define NT 25000
#define EAA 800000
#define EAT 400000
#define ETA 400000
#define NSEG 125000          // NA + NA + NT rows: [aa | ta | at]
#define TOTAL_E 1600000
#define NB 245               // coarse buckets of 512 rows
#define NBLK1 196            // pass-1 blocks
#define CHUNK 8192           // edges per pass-1 block

// ---- workspace layout (4-byte element offsets) ----
#define O_HIST    0          // int[48020]: hist[bucket][block] -> scanned bases
#define O_ATSRC   48064      // int[50000]: at-relation src out-degree (over NA)
#define O_TASRC   98064      // int[25000]: ta-relation src out-degree (over NT)
#define O_RO      123072     // int[125001]: CSR row offsets
#define O_CAA     248128     // float[50000]: rsqrt(indeg_aa+1)
#define O_CTAD    298128     // float[50000]: ta dst coef (over NA)
#define O_CATD    348128     // float[25000]: at dst coef (over NT)
#define O_CATS    373128     // float[50000]: at src coef (over NA)
#define O_CTAS    423128     // float[25000]: ta src coef (over NT)
#define O_U       448128     // float[512]: U_aa[128] | U_ta[128] | U_at[128] | v[4]
#define O_P       448640     // float[100000]: p' = (h_a @ U_aa) * c_aa
#define O_Q       548640     // float[100000]: q' = (h_a @ U_at) * c_ats
#define O_R       648640     // float[50000]:  r' = (h_t @ U_ta) * c_tas
#define O_REC     698640     // int[1600000]: packed records (row_local<<16)|src
#define O_CSR     2298640    // ushort[1600000]: final CSR src indices

// ---------- pass 1a: per-block coarse histogram (LDS) + fused src-degree atomics ----------
__global__ void __launch_bounds__(256)
p1_hist_kernel(const int* __restrict__ dst_aa, const int* __restrict__ dst_ta,
               const int* __restrict__ dst_at, const int* __restrict__ src_ta,
               const int* __restrict__ src_at, int* __restrict__ wi) {
    __shared__ int h[NB];
    for (int i = threadIdx.x; i < NB; i += 256) h[i] = 0;
    __syncthreads();
    int b = blockIdx.x;
    int t0 = b * CHUNK, t1 = min(t0 + CHUNK, TOTAL_E);
    for (int t = t0 + threadIdx.x; t < t1; t += 256) {
        int row;
        if (t < EAA) {
            row = dst_aa[t];
        } else if (t < EAA + ETA) {
            int u = t - EAA;
            row = NA + dst_ta[u];
            atomicAdd(&wi[O_TASRC + src_ta[u]], 1);
        } else {
            int u = t - EAA - ETA;
            row = 2 * NA + dst_at[u];
            atomicAdd(&wi[O_ATSRC + src_at[u]], 1);
        }
        atomicAdd(&h[row >> 9], 1);
    }
    __syncthreads();
    for (int i = threadIdx.x; i < NB; i += 256) wi[O_HIST + i * NBLK1 + b] = h[i];
}

// ---------- aux: block 0 = hist scan; blocks 1..74 = src coefs; block 75 = U fuse ----------
__global__ void __launch_bounds__(1024)
aux_kernel(int* __restrict__ wi, float* __restrict__ wf,
           const float* __restrict__ W2_aa, const float* __restrict__ W2_ta,
           const float* __restrict__ W2_at, const float* __restrict__ b2_aa,
           const float* __restrict__ b2_ta, const float* __restrict__ b2_at,
           const float* __restrict__ Wp_a, const float* __restrict__ bp_a,
           const float* __restrict__ Wp_t, const float* __restrict__ bp_t) {
    if (blockIdx.x == 0) {
        // exclusive scan of hist[NB*NBLK1]
        __shared__ int wsum[16];
        __shared__ int sCarry;
        int* h = wi + O_HIST;
        int tid = threadIdx.x, lane = tid & 63, wid = tid >> 6;
        if (tid == 0) sCarry = 0;
        __syncthreads();
        const int N2 = NB * NBLK1;
        for (int base = 0; base < N2; base += 1024) {
            int idx = base + tid;
            int v = (idx < N2) ? h[idx] : 0;
            int x = v;
#pragma unroll
            for (int off = 1; off < 64; off <<= 1) {
                int y = __shfl_up(x, off, 64);
                if (lane >= off) x += y;
            }
            if (lane == 63) wsum[wid] = x;
            __syncthreads();
            int wpre = 0, tot = 0;
            for (int w = 0; w < 16; ++w) {
                int s = wsum[w];
                if (w < wid) wpre += s;
                tot += s;
            }
            int excl = x - v + wpre + sCarry;
            if (idx < N2) h[idx] = excl;
            __syncthreads();
            if (tid == 0) sCarry += tot;
            __syncthreads();
        }
    } else if (blockIdx.x <= 74) {
        int t = (blockIdx.x - 1) * 1024 + threadIdx.x;
        if (t < 50000) {
            int d = wi[O_ATSRC + t];
            wf[O_CATS + t] = d > 0 ? rsqrtf((float)d) : 0.0f;
        } else if (t < 75000) {
            int i = t - 50000; int d = wi[O_TASRC + i];
            wf[O_CTAS + i] = d > 0 ? rsqrtf((float)d) : 0.0f;
        }
    } else {
        float* U = wf + O_U;
        int t = threadIdx.x;
        if (t < 128) {
            int k = t >> 1, j = t & 1;
            float a = 0.f;
            for (int f = 0; f < 64; ++f) a = fmaf(W2_aa[k * 64 + f], Wp_a[f * 2 + j], a);
            U[t] = a;
        } else if (t < 256) {
            int u = t - 128; int k = u >> 1, j = u & 1;
            float a = 0.f;
            for (int f = 0; f < 64; ++f) a = fmaf(W2_ta[k * 64 + f], Wp_a[f * 2 + j], a);
            U[128 + u] = a;
        } else if (t < 384) {
            int u = t - 256; int k = u >> 1, j = u & 1;
            float a = 0.f;
            for (int f = 0; f < 64; ++f) a = fmaf(W2_at[k * 64 + f], Wp_t[f * 2 + j], a);
            U[256 + u] = a;
        } else if (t < 386) {
            int j = t - 384;
            float a = bp_a[j];
            for (int f = 0; f < 64; ++f) a = fmaf(b2_aa[f] + b2_ta[f], Wp_a[f * 2 + j], a);
            U[384 + j] = a;
        } else if (t < 388) {
            int j = t - 386;
            float a = bp_t[j];
            for (int f = 0; f < 64; ++f) a = fmaf(b2_at[f], Wp_t[f * 2 + j], a);
            U[386 + j] = a;
        }
    }
}

// ---------- pass 1c: scatter packed records via LDS cursors (block-exclusive runs) ----------
__global__ void __launch_bounds__(256)
p1_scatter_kernel(const int* __restrict__ src_aa, const int* __restrict__ dst_aa,
                  const int* __restrict__ src_ta, const int* __restrict__ dst_ta,
                  const int* __restrict__ src_at, const int* __restrict__ dst_at,
                  const int* __restrict__ hist_g, int* __restrict__ rec) {
    __shared__ int cur[NB];
    int b = blockIdx.x;
    for (int i = threadIdx.x; i < NB; i += 256) cur[i] = hist_g[i * NBLK1 + b];
    __syncthreads();
    int t0 = b * CHUNK, t1 = min(t0 + CHUNK, TOTAL_E);
    for (int t = t0 + threadIdx.x; t < t1; t += 256) {
        int row, s;
        if (t < EAA) { row = dst_aa[t]; s = src_aa[t]; }
        else if (t < EAA + ETA) { int u = t - EAA; row = NA + dst_ta[u]; s = src_ta[u]; }
        else { int u = t - EAA - ETA; row = 2 * NA + dst_at[u]; s = src_at[u]; }
        int pos = atomicAdd(&cur[row >> 9], 1);
        rec[pos] = ((row & 511) << 16) | s;
    }
}

// ---------- pass 2: per-bucket degree count + LDS scan -> ro + dst coefs + CSR scatter ----------
__global__ void __launch_bounds__(256)
p2_kernel(const int* __restrict__ hist_g, const int* __restrict__ rec,
          int* __restrict__ ro, float* __restrict__ caa, float* __restrict__ ctad,
          float* __restrict__ catd, unsigned short* __restrict__ csr) {
    __shared__ int deg[512];
    __shared__ int rb[512];
    __shared__ int wsum[4];
    int k = blockIdx.x, tid = threadIdx.x, lane = tid & 63, wid = tid >> 6;
    int e0 = hist_g[k * NBLK1];
    int e1 = (k + 1 < NB) ? hist_g[(k + 1) * NBLK1] : TOTAL_E;
    deg[tid] = 0; deg[tid + 256] = 0;
    __syncthreads();
    for (int j = e0 + tid; j < e1; j += 256) atomicAdd(&deg[rec[j] >> 16], 1);
    __syncthreads();
    int d0 = deg[2 * tid], d1 = deg[2 * tid + 1];
    int v = d0 + d1;
    int x = v;
#pragma unroll
    for (int off = 1; off < 64; off <<= 1) {
        int y = __shfl_up(x, off, 64);
        if (lane >= off) x += y;
    }
    if (lane == 63) wsum[wid] = x;
    __syncthreads();
    int wpre = 0;
    for (int w = 0; w < wid; ++w) wpre += wsum[w];
    int pexcl = x - v + wpre;
    rb[2 * tid] = e0 + pexcl;
    rb[2 * tid + 1] = e0 + pexcl + d0;
    __syncthreads();
    for (int i = tid; i < 512; i += 256) {
        int g = k * 512 + i;
        if (g < NSEG) {
            ro[g] = rb[i];
            int d = deg[i];
            if (g < NA) caa[g] = rsqrtf((float)d + 1.0f);
            else if (g < 2 * NA) ctad[g - NA] = d > 0 ? rsqrtf((float)d) : 0.0f;
            else catd[g - 2 * NA] = d > 0 ? rsqrtf((float)d) : 0.0f;
        }
    }
    if (k == NB - 1 && tid == 0) ro[NSEG] = TOTAL_E;
    __syncthreads();
    for (int j = e0 + tid; j < e1; j += 256) {
        int rc = rec[j];
        int pos = atomicAdd(&rb[rc >> 16], 1);
        csr[pos] = (unsigned short)(rc & 0xFFFF);
    }
}

// ---------- conv1 fused (agents | targets by block range), index-preloaded gather ----------
__global__ void __launch_bounds__(256)
conv1_all_kernel(const float* __restrict__ x_a, const float* __restrict__ x_t,
                 const int* __restrict__ ro, const unsigned short* __restrict__ csr,
                 const float* __restrict__ c_aa, const float* __restrict__ c_ta_d,
                 const float* __restrict__ c_ta_s, const float* __restrict__ c_at_s,
                 const float* __restrict__ c_at_d,
                 const float* __restrict__ W_aa, const float* __restrict__ b_aa,
                 const float* __restrict__ W_ta, const float* __restrict__ b_ta,
                 const float* __restrict__ W_at, const float* __restrict__ b_at,
                 const float* __restrict__ U,
                 float* __restrict__ p, float* __restrict__ q, float* __restrict__ r) {
    __shared__ float sW0[2048];
    __shared__ float sW1[2048];
    __shared__ float sAgg[4][2][32];
    int lane = threadIdx.x & 63;
    int wave = threadIdx.x >> 6;
    int e8 = lane >> 3, k4 = lane & 7;

    if (blockIdx.x < NA / 4) {
        // ---------- agents ----------
        for (int i = threadIdx.x; i < 2048; i += 256) {
            sW0[i] = W_aa[i];
            sW1[i] = W_ta[i];
        }
        int i = blockIdx.x * 4 + wave;
        float ci = c_aa[i];
        int b0 = ro[i], e0v = ro[i + 1];
        int b1 = ro[NA + i], e1v = ro[NA + i + 1];
        int na = e0v - b0, nt = e1v - b1;
        // coalesced index preload (up to 64 per row)
        int sA = (lane < na) ? (int)csr[b0 + lane] : -1;
        int sT = (lane < nt) ? (int)csr[b1 + lane] : -1;

        float4 accA = make_float4(0.f, 0.f, 0.f, 0.f);
        int ngA = min(na, 64);
        for (int g = 0; g * 8 < ngA; ++g) {
            int s = __shfl(sA, g * 8 + e8, 64);
            if (s >= 0) {
                float w = c_aa[s];
                float4 xv = *(const float4*)(x_a + (size_t)s * 32 + k4 * 4);
                accA.x = fmaf(xv.x, w, accA.x);
                accA.y = fmaf(xv.y, w, accA.y);
                accA.z = fmaf(xv.z, w, accA.z);
                accA.w = fmaf(xv.w, w, accA.w);
            }
        }
        for (int j = b0 + 64 + e8; j < e0v; j += 8) {   // rare tail
            int s = csr[j];
            float w = c_aa[s];
            float4 xv = *(const float4*)(x_a + (size_t)s * 32 + k4 * 4);
            accA.x = fmaf(xv.x, w, accA.x);
            accA.y = fmaf(xv.y, w, accA.y);
            accA.z = fmaf(xv.z, w, accA.z);
            accA.w = fmaf(xv.w, w, accA.w);
        }
        if (e8 == 0) {  // self-loop
            float4 xv = *(const float4*)(x_a + (size_t)i * 32 + k4 * 4);
            accA.x = fmaf(xv.x, ci, accA.x);
            accA.y = fmaf(xv.y, ci, accA.y);
            accA.z = fmaf(xv.z, ci, accA.z);
            accA.w = fmaf(xv.w, ci, accA.w);
        }
        float4 accT = make_float4(0.f, 0.f, 0.f, 0.f);
        int ngT = min(nt, 64);
        for (int g = 0; g * 8 < ngT; ++g) {
            int s = __shfl(sT, g * 8 + e8, 64);
            if (s >= 0) {
                float w = c_ta_s[s];
                float4 xv = *(const float4*)(x_t + (size_t)s * 32 + k4 * 4);
                accT.x = fmaf(xv.x, w, accT.x);
                accT.y = fmaf(xv.y, w, accT.y);
                accT.z = fmaf(xv.z, w, accT.z);
                accT.w = fmaf(xv.w, w, accT.w);
            }
        }
        for (int j = b1 + 64 + e8; j < e1v; j += 8) {   // rare tail
            int s = csr[j];
            float w = c_ta_s[s];
            float4 xv = *(const float4*)(x_t + (size_t)s * 32 + k4 * 4);
            accT.x = fmaf(xv.x, w, accT.x);
            accT.y = fmaf(xv.y, w, accT.y);
            accT.z = fmaf(xv.z, w, accT.z);
            accT.w = fmaf(xv.w, w, accT.w);
        }
#pragma unroll
        for (int m = 8; m <= 32; m <<= 1) {
            accA.x += __shfl_xor(accA.x, m, 64);
            accA.y += __shfl_xor(accA.y, m, 64);
            accA.z += __shfl_xor(accA.z, m, 64);
            accA.w += __shfl_xor(accA.w, m, 64);
            accT.x += __shfl_xor(accT.x, m, 64);
            accT.y += __shfl_xor(accT.y, m, 64);
            accT.z += __shfl_xor(accT.z, m, 64);
            accT.w += __shfl_xor(accT.w, m, 64);
        }
        if (lane < 8) {
            float cta = c_ta_d[i];
            *(float4*)&sAgg[wave][0][k4 * 4] =
                make_float4(accA.x * ci, accA.y * ci, accA.z * ci, accA.w * ci);
            *(float4*)&sAgg[wave][1][k4 * 4] =
                make_float4(accT.x * cta, accT.y * cta, accT.z * cta, accT.w * cta);
        }
        __syncthreads();
        float h = b_aa[lane] + b_ta[lane];
#pragma unroll
        for (int kk = 0; kk < 32; ++kk) {
            h = fmaf(sAgg[wave][0][kk], sW0[kk * 64 + lane], h);
            h = fmaf(sAgg[wave][1][kk], sW1[kk * 64 + lane], h);
        }
        h = fmaxf(h, 0.f);
        float p0 = h * U[lane * 2], p1 = h * U[lane * 2 + 1];
        float q0 = h * U[256 + lane * 2], q1 = h * U[256 + lane * 2 + 1];
#pragma unroll
        for (int m = 32; m; m >>= 1) {
            p0 += __shfl_xor(p0, m, 64);
            p1 += __shfl_xor(p1, m, 64);
            q0 += __shfl_xor(q0, m, 64);
            q1 += __shfl_xor(q1, m, 64);
        }
        if (lane == 0) {
            float cq = c_at_s[i];
            *(float2*)&p[i * 2] = make_float2(p0 * ci, p1 * ci);
            *(float2*)&q[i * 2] = make_float2(q0 * cq, q1 * cq);
        }
    } else {
        // ---------- targets ----------
        for (int i = threadIdx.x; i < 2048; i += 256) sW0[i] = W_at[i];
        int i = (blockIdx.x - NA / 4) * 4 + wave;
        int b0 = ro[2 * NA + i], e0v = ro[2 * NA + i + 1];
        int na = e0v - b0;
        int sA = (lane < na) ? (int)csr[b0 + lane] : -1;
        float4 acc = make_float4(0.f, 0.f, 0.f, 0.f);
        int ng = min(na, 64);
        for (int g = 0; g * 8 < ng; ++g) {
            int s = __shfl(sA, g * 8 + e8, 64);
            if (s >= 0) {
                float w = c_at_s[s];
                float4 xv = *(const float4*)(x_a + (size_t)s * 32 + k4 * 4);
                acc.x = fmaf(xv.x, w, acc.x);
                acc.y = fmaf(xv.y, w, acc.y);
                acc.z = fmaf(xv.z, w, acc.z);
                acc.w = fmaf(xv.w, w, acc.w);
            }
        }
        for (int j = b0 + 64 + e8; j < e0v; j += 8) {   // rare tail
            int s = csr[j];
            float w = c_at_s[s];
            float4 xv = *(const float4*)(x_a + (size_t)s * 32 + k4 * 4);
            acc.x = fmaf(xv.x, w, acc.x);
            acc.y = fmaf(xv.y, w, acc.y);
            acc.z = fmaf(xv.z, w, acc.z);
            acc.w = fmaf(xv.w, w, acc.w);
        }
#pragma unroll
        for (int m = 8; m <= 32; m <<= 1) {
            acc.x += __shfl_xor(acc.x, m, 64);
            acc.y += __shfl_xor(acc.y, m, 64);
            acc.z += __shfl_xor(acc.z, m, 64);
            acc.w += __shfl_xor(acc.w, m, 64);
        }
        if (lane < 8) {
            float cd = c_at_d[i];
            *(float4*)&sAgg[wave][0][k4 * 4] =
                make_float4(acc.x * cd, acc.y * cd, acc.z * cd, acc.w * cd);
        }
        __syncthreads();
        float h = b_at[lane];
#pragma unroll
        for (int kk = 0; kk < 32; ++kk) h = fmaf(sAgg[wave][0][kk], sW0[kk * 64 + lane], h);
        h = fmaxf(h, 0.f);
        float r0 = h * U[128 + lane * 2], r1 = h * U[128 + lane * 2 + 1];
#pragma unroll
        for (int m = 32; m; m >>= 1) {
            r0 += __shfl_xor(r0, m, 64);
            r1 += __shfl_xor(r1, m, 64);
        }
        if (lane == 0) {
            float cr = c_ta_s[i];
            *(float2*)&r[i * 2] = make_float2(r0 * cr, r1 * cr);
        }
    }
}

// ---------- conv2+proj: one wave per node, 32 edge slots x 2 comps ----------
__global__ void __launch_bounds__(256)
out_all_kernel(const float* __restrict__ p, const float* __restrict__ q,
               const float* __restrict__ r, const int* __restrict__ ro,
               const unsigned short* __restrict__ csr,
               const float* __restrict__ c_aa, const float* __restrict__ c_ta_d,
               const float* __restrict__ c_at_d, const float* __restrict__ U,
               float* __restrict__ out) {
    int wgid = blockIdx.x * 4 + (threadIdx.x >> 6);
    int lane = threadIdx.x & 63;
    int slot = lane >> 1, j = lane & 1;
    if (wgid < NA) {
        int i = wgid;
        int b0 = ro[i], n0 = ro[i + 1] - b0;
        float accA = (slot == 0) ? p[i * 2 + j] : 0.f;   // self-loop (p premultiplied)
        for (int e = slot; e < n0; e += 32) accA += p[(int)csr[b0 + e] * 2 + j];
        int b1 = ro[NA + i], n1 = ro[NA + i + 1] - b1;
        float accT = 0.f;
        for (int e = slot; e < n1; e += 32) accT += r[(int)csr[b1 + e] * 2 + j];
#pragma unroll
        for (int m = 2; m <= 32; m <<= 1) {
            accA += __shfl_xor(accA, m, 64);
            accT += __shfl_xor(accT, m, 64);
        }
        if (lane < 2) out[i * 2 + j] = U[384 + j] + accA * c_aa[i] + accT * c_ta_d[i];
    } else {
        int i = wgid - NA;
        int b0 = ro[2 * NA + i], n0 = ro[2 * NA + i + 1] - b0;
        float acc = 0.f;
        for (int e = slot; e < n0; e += 32) acc += q[(int)csr[b0 + e] * 2 + j];
#pragma unroll
        for (int m = 2; m <= 32; m <<= 1) acc += __shfl_xor(acc, m, 64);
        if (lane < 2) out[NA * 2 + i * 2 + j] = U[386 + j] + acc * c_at_d[i];
    }
}

extern "C" void kernel_launch(void* const* d_in, const int* in_sizes, int n_in,
                              void* d_out, int out_size, void* d_ws, size_t ws_size,
                              hipStream_t stream) {
    const float* x_a   = (const float*)d_in[1];
    const float* x_t   = (const float*)d_in[2];
    const int* src_aa  = (const int*)d_in[3];
    const int* dst_aa  = (const int*)d_in[4];
    const int* src_at  = (const int*)d_in[5];
    const int* dst_at  = (const int*)d_in[6];
    const int* src_ta  = (const int*)d_in[7];
    const int* dst_ta  = (const int*)d_in[8];
    const float* W1_aa = (const float*)d_in[9];
    const float* b1_aa = (const float*)d_in[10];
    const float* W1_at = (const float*)d_in[11];
    const float* b1_at = (const float*)d_in[12];
    const float* W1_ta = (const float*)d_in[13];
    const float* b1_ta = (const float*)d_in[14];
    const float* W2_aa = (const float*)d_in[15];
    const float* b2_aa = (const float*)d_in[16];
    const float* W2_at = (const float*)d_in[17];
    const float* b2_at = (const float*)d_in[18];
    const float* W2_ta = (const float*)d_in[19];
    const float* b2_ta = (const float*)d_in[20];
    const float* Wp_a  = (const float*)d_in[21];
    const float* bp_a  = (const float*)d_in[22];
    const float* Wp_t  = (const float*)d_in[23];
    const float* bp_t  = (const float*)d_in[24];

    int*   wi  = (int*)d_ws;
    float* wf  = (float*)d_ws;
    unsigned short* csr = (unsigned short*)(wi + O_CSR);
    float* out = (float*)d_out;

    // zero the src-degree histograms
    hipMemsetAsync(wi + O_ATSRC, 0, 75000 * 4, stream);

    // pass 1: coarse bucket histogram (+ fused src degrees)
    p1_hist_kernel<<<NBLK1, 256, 0, stream>>>(dst_aa, dst_ta, dst_at, src_ta, src_at, wi);

    // scan + src coefs + U fuse in one dispatch
    aux_kernel<<<76, 1024, 0, stream>>>(wi, wf, W2_aa, W2_ta, W2_at, b2_aa, b2_ta, b2_at,
                                        Wp_a, bp_a, Wp_t, bp_t);

    // pass 1c: bucket scatter of packed records
    p1_scatter_kernel<<<NBLK1, 256, 0, stream>>>(src_aa, dst_aa, src_ta, dst_ta,
                                                 src_at, dst_at, wi + O_HIST, wi + O_REC);

    // pass 2: per-bucket -> ro + dst coefs + final CSR
    p2_kernel<<<NB, 256, 0, stream>>>(wi + O_HIST, wi + O_REC, wi + O_RO,
                                      wf + O_CAA, wf + O_CTAD, wf + O_CATD, csr);

    // conv1 fused (agents + targets), index-preloaded gathers
    conv1_all_kernel<<<NA / 4 + NT / 4, 256, 0, stream>>>(
        x_a, x_t, wi + O_RO, csr, wf + O_CAA, wf + O_CTAD, wf + O_CTAS, wf + O_CATS,
        wf + O_CATD, W1_aa, b1_aa, W1_ta, b1_ta, W1_at, b1_at, wf + O_U,
        wf + O_P, wf + O_Q, wf + O_R);

    // conv2 + projection, wave per node
    out_all_kernel<<<(NA + NT) / 4, 256, 0, stream>>>(
        wf + O_P, wf + O_Q, wf + O_R, wi + O_RO, csr,
        wf + O_CAA, wf + O_CTAD, wf + O_CATD, wf + O_U, out);
}